// Round 1
// baseline (136.968 us; speedup 1.0000x reference)
//
#include <hip/hip_runtime.h>
#include <hip/hip_bf16.h>
#include <math.h>

#define B_ 4
#define S_ 2048
#define E_ 1024
#define H_ 64
#define NQT 32          // S/64 q-tiles
#define SPLITS 8
#define TPS 4           // 64-key tiles per split (256 keys/split)

typedef short bf16x8 __attribute__((ext_vector_type(8)));
typedef float f32x4 __attribute__((ext_vector_type(4)));
typedef unsigned short u16x8 __attribute__((ext_vector_type(8)));
typedef unsigned short u16x4 __attribute__((ext_vector_type(4)));

__device__ __forceinline__ unsigned short f2bf(float f){
    unsigned u = __builtin_bit_cast(unsigned, f);
    u += 0x7fffu + ((u >> 16) & 1u);          // RNE
    return (unsigned short)(u >> 16);
}
__device__ __forceinline__ float bf2f(unsigned short h){
    return __builtin_bit_cast(float, ((unsigned)h) << 16);
}
#define MFMA16(a,b,c) __builtin_amdgcn_mfma_f32_16x16x32_bf16((a),(b),(c),0,0,0)

// ---------------------------------------------------------------------------
// Kernel 1: QKV projection.  C[8192x64] = x[8192x1024] @ W[64x1024]^T per comp.
// hi/lo bf16 split of both operands -> fp32-accurate result; Q,K stored as
// hi/lo bf16 pairs, V stored transposed [b][h][s] single bf16.
// grid (128 Mtiles, 3 comps), block 256 (4 waves x 16 rows).
// ---------------------------------------------------------------------------
__global__ __launch_bounds__(256) void qkv_kernel(
    const float* __restrict__ x, const float* __restrict__ Wq,
    const float* __restrict__ Wk, const float* __restrict__ Wv,
    unsigned short* __restrict__ Qhi, unsigned short* __restrict__ Qlo,
    unsigned short* __restrict__ Khi, unsigned short* __restrict__ Klo,
    unsigned short* __restrict__ Vt)
{
    __shared__ unsigned short Ah[64*64], Al[64*64], Bh[64*64], Bl[64*64];
    const int m0 = blockIdx.x * 64;
    const int comp = blockIdx.y;
    const float* W = (comp==0) ? Wq : (comp==1) ? Wk : Wv;
    const int tid = threadIdx.x;
    const int lane = tid & 63, wv = tid >> 6, l15 = lane & 15, quad = lane >> 4;

    f32x4 acc[4];
    #pragma unroll
    for (int i=0;i<4;i++) acc[i] = f32x4{0.f,0.f,0.f,0.f};

    const int arow = tid >> 2;          // 0..63 staging row
    const int ag0  = (tid & 3) * 2;     // first of two 8-elem groups

    for (int k0 = 0; k0 < E_; k0 += 64) {
        const float* xs = x + (size_t)(m0 + arow)*E_ + k0 + ag0*8;
        float4 xa = ((const float4*)xs)[0];
        float4 xb = ((const float4*)xs)[1];
        float4 xc = ((const float4*)xs)[2];
        float4 xd = ((const float4*)xs)[3];
        const float* wsrc = W + (size_t)arow*E_ + k0 + ag0*8;
        float4 wa = ((const float4*)wsrc)[0];
        float4 wb = ((const float4*)wsrc)[1];
        float4 wc = ((const float4*)wsrc)[2];
        float4 wd = ((const float4*)wsrc)[3];
        __syncthreads();   // previous iter's frag reads done
        auto put = [&](unsigned short* hi_t, unsigned short* lo_t, int g, float4 p, float4 q2){
            u16x8 hv, lv;
            float vv[8] = {p.x,p.y,p.z,p.w,q2.x,q2.y,q2.z,q2.w};
            #pragma unroll
            for (int j=0;j<8;j++){ unsigned short h = f2bf(vv[j]); hv[j]=h; lv[j]=f2bf(vv[j]-bf2f(h)); }
            int idx = arow*8 + (g ^ (arow & 7));   // XOR swizzle for bank spread
            ((u16x8*)hi_t)[idx] = hv; ((u16x8*)lo_t)[idx] = lv;
        };
        put(Ah, Al, ag0,   xa, xb);
        put(Ah, Al, ag0+1, xc, xd);
        put(Bh, Bl, ag0,   wa, wb);
        put(Bh, Bl, ag0+1, wc, wd);
        __syncthreads();
        #pragma unroll
        for (int kk=0; kk<2; kk++){
            const int arw = wv*16 + l15;
            bf16x8 ah = ((const bf16x8*)Ah)[arw*8 + ((kk*4+quad) ^ (l15 & 7))];
            bf16x8 al = ((const bf16x8*)Al)[arw*8 + ((kk*4+quad) ^ (l15 & 7))];
            #pragma unroll
            for (int nt=0; nt<4; nt++){
                const int brw = nt*16 + l15;
                bf16x8 bh = ((const bf16x8*)Bh)[brw*8 + ((kk*4+quad) ^ (l15 & 7))];
                bf16x8 bl = ((const bf16x8*)Bl)[brw*8 + ((kk*4+quad) ^ (l15 & 7))];
                acc[nt] = MFMA16(ah, bh, acc[nt]);   // hi*hi
                acc[nt] = MFMA16(ah, bl, acc[nt]);   // hi*lo
                acc[nt] = MFMA16(al, bh, acc[nt]);   // lo*hi
            }
        }
    }
    // epilogue: C/D layout col=l15(+16nt), row=quad*4+r
    if (comp < 2) {
        unsigned short* dh = (comp==0) ? Qhi : Khi;
        unsigned short* dl = (comp==0) ? Qlo : Klo;
        #pragma unroll
        for (int nt=0; nt<4; nt++)
        #pragma unroll
        for (int r=0; r<4; r++){
            int row = m0 + wv*16 + quad*4 + r;
            float v = acc[nt][r];
            unsigned short h = f2bf(v);
            dh[(size_t)row*H_ + nt*16 + l15] = h;
            dl[(size_t)row*H_ + nt*16 + l15] = f2bf(v - bf2f(h));
        }
    } else {
        int b = m0 >> 11;
        int s0 = (m0 & (S_-1)) + wv*16 + quad*4;
        #pragma unroll
        for (int nt=0; nt<4; nt++){
            u16x4 pk;
            #pragma unroll
            for (int r=0;r<4;r++) pk[r] = f2bf(acc[nt][r]);
            *(u16x4*)(Vt + (size_t)b*H_*S_ + (size_t)(nt*16+l15)*S_ + s0) = pk;
        }
    }
}

// ---------------------------------------------------------------------------
// Kernel 2: mean of V per (b,h) — exact substitute for fully-masked rows
// (reference gives uniform softmax over ALL 2048 keys there).
// ---------------------------------------------------------------------------
__global__ __launch_bounds__(256) void meanv_kernel(const unsigned short* __restrict__ Vt,
                                                    float* __restrict__ meanV)
{
    int b = blockIdx.x >> 6, h = blockIdx.x & 63;
    const unsigned short* src = Vt + (size_t)b*H_*S_ + (size_t)h*S_;
    float sum = 0.f;
    for (int j = threadIdx.x; j < S_; j += 256) sum += bf2f(src[j]);
    #pragma unroll
    for (int m=32; m>=1; m>>=1) sum += __shfl_xor(sum, m);
    __shared__ float red[4];
    if ((threadIdx.x & 63) == 0) red[threadIdx.x >> 6] = sum;
    __syncthreads();
    if (threadIdx.x == 0) meanV[b*H_ + h] = (red[0]+red[1]+red[2]+red[3]) * (1.f/S_);
}

// ---------------------------------------------------------------------------
// Kernel 3: flash attention, split-K (flash-decoding).  Block = 64 q-rows
// (4 waves x 16), one split of TPS 64-key tiles.  Online softmax in fp32;
// QK^T with hi/lo bf16 (fp32-accurate logits); PV single bf16.
// Partials (m,l,O) to workspace; combine kernel merges.
// ---------------------------------------------------------------------------
__global__ __launch_bounds__(256) void attn_kernel(
    const unsigned short* __restrict__ Qhi, const unsigned short* __restrict__ Qlo,
    const unsigned short* __restrict__ Khi, const unsigned short* __restrict__ Klo,
    const unsigned short* __restrict__ Vt, const int* __restrict__ pad,
    float* __restrict__ Opart, float* __restrict__ mpart, float* __restrict__ lpart)
{
    const int qt = blockIdx.x, b = blockIdx.y, sp = blockIdx.z;
    const int t0 = sp * TPS;
    if (t0 > qt) return;                       // causal: tiles 0..qt only
    const int t1 = min(t0 + TPS, qt + 1);

    __shared__ unsigned short KtH[64*64], KtL[64*64], Vts[64*64];
    __shared__ unsigned short Ps[4][64*20];    // per-wave P^T scratch, stride 20
    __shared__ int pad_s[64];

    const int tid = threadIdx.x, lane = tid & 63, wv = tid >> 6, l15 = lane & 15, quad = lane >> 4;
    const int role = tid >> 6, srow = tid & 63;

    // Q fragments (A-operand: m=l15 row, k=quad*8+j), held in regs all kernel
    const size_t qrow = (size_t)(b*S_ + qt*64 + wv*16 + l15);
    bf16x8 aqh0 = *(const bf16x8*)(Qhi + qrow*H_ + quad*8);
    bf16x8 aqh1 = *(const bf16x8*)(Qhi + qrow*H_ + 32 + quad*8);
    bf16x8 aql0 = *(const bf16x8*)(Qlo + qrow*H_ + quad*8);
    bf16x8 aql1 = *(const bf16x8*)(Qlo + qrow*H_ + 32 + quad*8);

    float m_i[4], l_i[4];
    f32x4 o[4];
    #pragma unroll
    for (int r=0;r<4;r++){ m_i[r] = -INFINITY; l_i[r] = 0.f; }
    #pragma unroll
    for (int i=0;i<4;i++) o[i] = f32x4{0.f,0.f,0.f,0.f};

    const int qg = qt*64 + wv*16 + quad*4;     // + r = global q row
    unsigned short* Pw = &Ps[wv][0];

    for (int t = t0; t < t1; ++t) {
        const int kb = t * 64;
        __syncthreads();
        if (role < 3) {                        // stage KtH / KtL / Vts (one row/thread)
            const unsigned short* gs =
                (role==0) ? (Khi + ((size_t)(b*S_ + kb + srow))*H_) :
                (role==1) ? (Klo + ((size_t)(b*S_ + kb + srow))*H_) :
                            (Vt + (size_t)b*H_*S_ + (size_t)srow*S_ + kb);
            unsigned short* ld = (role==0) ? KtH : (role==1) ? KtL : Vts;
            #pragma unroll
            for (int i=0;i<8;i++){
                u16x8 d = ((const u16x8*)gs)[i];
                ((u16x8*)ld)[srow*8 + (i ^ (srow & 7))] = d;
            }
        } else {
            pad_s[srow] = pad[b*S_ + kb + srow];
        }
        __syncthreads();

        // --- S = Q K^T (hi/lo: fp32-accurate) ---
        f32x4 s[4];
        #pragma unroll
        for (int nt=0; nt<4; nt++){
            const int krw = nt*16 + l15;
            bf16x8 bh0 = ((const bf16x8*)KtH)[krw*8 + ((quad)   ^ (l15 & 7))];
            bf16x8 bh1 = ((const bf16x8*)KtH)[krw*8 + ((4+quad) ^ (l15 & 7))];
            bf16x8 bl0 = ((const bf16x8*)KtL)[krw*8 + ((quad)   ^ (l15 & 7))];
            bf16x8 bl1 = ((const bf16x8*)KtL)[krw*8 + ((4+quad) ^ (l15 & 7))];
            f32x4 z = f32x4{0.f,0.f,0.f,0.f};
            z = MFMA16(aqh0, bh0, z);
            z = MFMA16(aqh1, bh1, z);
            z = MFMA16(aqh0, bl0, z);
            z = MFMA16(aqh1, bl1, z);
            z = MFMA16(aql0, bh0, z);
            z = MFMA16(aql1, bh1, z);
            s[nt] = z;
        }
        // --- mask + scale (exactly like reference: -1e9/8 where invalid) ---
        float rmax[4] = {-INFINITY,-INFINITY,-INFINITY,-INFINITY};
        #pragma unroll
        for (int nt=0; nt<4; nt++){
            const int kcol = nt*16 + l15;
            const int kg = kb + kcol;
            const int pv = pad_s[kcol];
            #pragma unroll
            for (int r=0;r<4;r++){
                bool ok = (kg <= qg + r) && (pv != 0);
                float v = ok ? s[nt][r]*0.125f : -1.25e8f;
                s[nt][r] = v;
                rmax[r] = fmaxf(rmax[r], v);
            }
        }
        #pragma unroll
        for (int msk=1; msk<=8; msk<<=1){
            #pragma unroll
            for (int r=0;r<4;r++) rmax[r] = fmaxf(rmax[r], __shfl_xor(rmax[r], msk));
        }
        float alpha[4];
        #pragma unroll
        for (int r=0;r<4;r++){
            float mn = fmaxf(m_i[r], rmax[r]);
            alpha[r] = __expf(m_i[r] - mn);     // expf(-inf)=0 on first tile
            m_i[r] = mn;
        }
        float rsum[4] = {0.f,0.f,0.f,0.f};
        #pragma unroll
        for (int nt=0; nt<4; nt++)
        #pragma unroll
        for (int r=0;r<4;r++){
            float p = __expf(s[nt][r] - m_i[r]); // fully-masked row: exp(0)=1 (uniform)
            s[nt][r] = p;
            rsum[r] += p;
        }
        #pragma unroll
        for (int msk=1; msk<=8; msk<<=1){
            #pragma unroll
            for (int r=0;r<4;r++) rsum[r] += __shfl_xor(rsum[r], msk);
        }
        #pragma unroll
        for (int r=0;r<4;r++) l_i[r] = l_i[r]*alpha[r] + rsum[r];
        #pragma unroll
        for (int hnt=0; hnt<4; hnt++)
        #pragma unroll
        for (int r=0;r<4;r++) o[hnt][r] *= alpha[r];

        // --- P: C-layout -> A-layout via per-wave LDS [key][20] ---
        #pragma unroll
        for (int nt=0; nt<4; nt++){
            const int key = nt*16 + l15;
            u16x4 pk;
            #pragma unroll
            for (int r=0;r<4;r++) pk[r] = f2bf(s[nt][r]);
            *(u16x4*)(Pw + key*20 + quad*4) = pk;   // rows quad*4..+3 contiguous
        }
        // --- O += P V ---
        #pragma unroll
        for (int ks=0; ks<2; ks++){
            bf16x8 ap;
            #pragma unroll
            for (int j=0;j<8;j++) ap[j] = (short)Pw[(ks*32 + quad*8 + j)*20 + l15];
            #pragma unroll
            for (int hnt=0; hnt<4; hnt++){
                bf16x8 bv = ((const bf16x8*)Vts)[(hnt*16+l15)*8 + ((ks*4+quad) ^ (l15 & 7))];
                o[hnt] = MFMA16(ap, bv, o[hnt]);
            }
        }
    }
    // store partials: [b][qt][sp][row 64][h 64]
    const size_t rbase = ((size_t)((b*NQT + qt)*SPLITS + sp))*64 + wv*16 + quad*4;
    if (l15 == 0) {
        #pragma unroll
        for (int r=0;r<4;r++){ mpart[rbase + r] = m_i[r]; lpart[rbase + r] = l_i[r]; }
    }
    #pragma unroll
    for (int hnt=0; hnt<4; hnt++)
    #pragma unroll
    for (int r=0;r<4;r++)
        Opart[(rbase + r)*H_ + hnt*16 + l15] = o[hnt][r];
}

// ---------------------------------------------------------------------------
// Kernel 4: merge split-K partials.  One thread per output element.
// ---------------------------------------------------------------------------
__global__ __launch_bounds__(256) void combine_kernel(
    const float* __restrict__ Opart, const float* __restrict__ mpart,
    const float* __restrict__ lpart, const float* __restrict__ meanV,
    float* __restrict__ out)
{
    const int idx = blockIdx.x*256 + threadIdx.x;
    const int h = idx & 63;
    const int q = (idx >> 6) & (S_-1);
    const int b = idx >> 17;
    const int qt = q >> 6, r = q & 63;
    const int ns = (qt >> 2) + 1;              // ceil((qt+1)/TPS)
    const size_t rb = ((size_t)(b*NQT + qt)*SPLITS)*64 + r;
    float M = -INFINITY;
    for (int s2=0; s2<ns; s2++) M = fmaxf(M, mpart[rb + (size_t)s2*64]);
    float res;
    if (M == -1.25e8f) {                       // no valid key anywhere: uniform over all 2048
        res = meanV[b*H_ + h];
    } else {
        float L = 0.f, acc = 0.f;
        for (int s2=0; s2<ns; s2++){
            float mi = mpart[rb + (size_t)s2*64];
            float wgt = __expf(mi - M);
            L += wgt * lpart[rb + (size_t)s2*64];
            acc += wgt * Opart[(rb + (size_t)s2*64)*H_ + h];
        }
        res = acc / L;
    }
    out[idx] = res;
}

// ---------------------------------------------------------------------------
// Workspace layout (bytes):
//   0        Qhi  1 MB          4 MB   Vt    1 MB
//   1 MB     Qlo  1 MB          5 MB   Opart 16 MB (fp32 partials)
//   2 MB     Khi  1 MB         21 MB   mpart 256 KB
//   3 MB     Klo  1 MB         21.25MB lpart 256 KB ; 21.5MB meanV 1 KB
// total ~21.5 MB
// ---------------------------------------------------------------------------
extern "C" void kernel_launch(void* const* d_in, const int* in_sizes, int n_in,
                              void* d_out, int out_size, void* d_ws, size_t ws_size,
                              hipStream_t stream)
{
    (void)in_sizes; (void)n_in; (void)out_size; (void)ws_size;
    const float* x  = (const float*)d_in[0];
    const int* pad  = (const int*)d_in[1];
    const float* Wq = (const float*)d_in[2];
    const float* Wk = (const float*)d_in[3];
    const float* Wv = (const float*)d_in[4];
    float* out = (float*)d_out;
    char* ws = (char*)d_ws;
    const size_t MB = 1u << 20;
    unsigned short* Qhi = (unsigned short*)(ws + 0*MB);
    unsigned short* Qlo = (unsigned short*)(ws + 1*MB);
    unsigned short* Khi = (unsigned short*)(ws + 2*MB);
    unsigned short* Klo = (unsigned short*)(ws + 3*MB);
    unsigned short* Vt  = (unsigned short*)(ws + 4*MB);
    float* Opart = (float*)(ws + 5*MB);
    float* mpart = (float*)(ws + 21*MB);
    float* lpart = (float*)(ws + 21*MB + (1u<<18));
    float* meanV = (float*)(ws + 21*MB + 2*(1u<<18));

    qkv_kernel<<<dim3(128,3), 256, 0, stream>>>(x, Wq, Wk, Wv, Qhi, Qlo, Khi, Klo, Vt);
    meanv_kernel<<<dim3(256), 256, 0, stream>>>(Vt, meanV);
    attn_kernel<<<dim3(NQT, B_, SPLITS), 256, 0, stream>>>(Qhi, Qlo, Khi, Klo, Vt, pad,
                                                           Opart, mpart, lpart);
    combine_kernel<<<dim3((B_*S_*H_)/256), 256, 0, stream>>>(Opart, mpart, lpart, meanV, out);
}